// Round 9
// baseline (241.611 us; speedup 1.0000x reference)
//
#include <hip/hip_runtime.h>

#define B_   64
#define T_   1024
#define C_   256
#define NEGF (-4294967295.0f)   // float(-2**32+1) == -2^32, matches reference fp32 cast
#define LN_EPS 1e-9f
#define XSTR 268                // fp32 transpose-tile row stride (floats)

typedef short  short8 __attribute__((ext_vector_type(8)));
typedef float  f32x4  __attribute__((ext_vector_type(4)));

union S8 { short8 v; unsigned int w[4]; };

// float -> bf16 (RNE), packed pair
__device__ __forceinline__ unsigned int pk2(float x, float y) {
  unsigned a = __float_as_uint(x); a = (a + 0x7fffu + ((a >> 16) & 1u)) >> 16;
  unsigned b = __float_as_uint(y); b = (b + 0x7fffu + ((b >> 16) & 1u)) >> 16;
  return a | (b << 16);
}

// async global->LDS, 16 B per lane
__device__ __forceinline__ void async16(const void* g, void* l) {
  __builtin_amdgcn_global_load_lds(
      (const __attribute__((address_space(1))) void*)g,
      (__attribute__((address_space(3))) void*)l,
      16, 0, 0);
}

// finalize one 16-row q-tile state: 1/l (or colsum fallback), LN, scaled
// atomic accumulate of the time-mean directly into out.
__device__ __forceinline__ void finalize_tile(
    f32x4* Oa, float m, float l, int b, int quad, int r,
    const float* __restrict__ colsum, const float* __restrict__ gamma,
    const float* __restrict__ beta, float* __restrict__ out)
{
  float mr[4], li[4];
#pragma unroll
  for (int reg = 0; reg < 4; ++reg) {
    mr[reg] = __shfl(m, quad * 4 + reg, 64);
    float lr = __shfl(l, quad * 4 + reg, 64);
    li[reg] = 1.f / lr;
  }
#pragma unroll
  for (int ct = 0; ct < 16; ++ct) {
    float cs = colsum[b * C_ + ct * 16 + r] * (1.0f / T_);
#pragma unroll
    for (int reg = 0; reg < 4; ++reg)
      Oa[ct][reg] = (mr[reg] < -1.0e9f) ? cs : Oa[ct][reg] * li[reg];
  }
  float ts[16];
#pragma unroll
  for (int ct = 0; ct < 16; ++ct) ts[ct] = 0.f;
#pragma unroll
  for (int reg = 0; reg < 4; ++reg) {
    float s2 = 0.f;
#pragma unroll
    for (int ct = 0; ct < 16; ++ct) s2 += Oa[ct][reg];
    s2 += __shfl_xor(s2, 1, 64); s2 += __shfl_xor(s2, 2, 64);
    s2 += __shfl_xor(s2, 4, 64); s2 += __shfl_xor(s2, 8, 64);
    float mu = s2 * (1.0f / C_);
    float sq = 0.f;
#pragma unroll
    for (int ct = 0; ct < 16; ++ct) { float d = Oa[ct][reg] - mu; sq += d * d; }
    sq += __shfl_xor(sq, 1, 64); sq += __shfl_xor(sq, 2, 64);
    sq += __shfl_xor(sq, 4, 64); sq += __shfl_xor(sq, 8, 64);
    float rstd = rsqrtf(sq * (1.0f / C_) + LN_EPS);
#pragma unroll
    for (int ct = 0; ct < 16; ++ct) {
      int c = ct * 16 + r;
      ts[ct] += gamma[c] * (Oa[ct][reg] - mu) * rstd + beta[c];
    }
  }
#pragma unroll
  for (int ct = 0; ct < 16; ++ct) {
    ts[ct] += __shfl_xor(ts[ct], 16, 64);
    ts[ct] += __shfl_xor(ts[ct], 32, 64);
  }
  if (quad == 0) {
#pragma unroll
    for (int ct = 0; ct < 16; ++ct)
      atomicAdd(&out[b * C_ + ct * 16 + r], ts[ct] * (1.0f / T_));
  }
}

// ---------------- fused kernel ----------------
// 256 blocks x 512 thr, 1 block/CU (128 KB LDS) -> ALL blocks co-resident,
// enabling device-scope flag sync. Block (b,t), t = q-tile pair (t,7-t).
// Phase 0: distributed mask-dtype scan + counter barrier (replaces detect).
// Phase A: convert rows [t*256,(t+1)*256) -> bf16 K image (row-swizzled) and
//          V^T image (chunk a = q*256 + ((c+4q)&255): producer-coalesced
//          writes, <=2-way consumer LDS reads) + colsum + sb; publish
//          ready-flag (threadfence + release).
// Main loop: flash5 structure verbatim (18 uniform 64-key tile iterations,
// ascending qt=t then descending qt=7-t, double-buffered DMA), with reads
// gated on quarter ready-flags. Epilogue writes straight to out.
__global__ __launch_bounds__(512, 2) void flash6(
    const float* __restrict__ x,
    const unsigned int* __restrict__ mw,
    const float* __restrict__ gamma,
    const float* __restrict__ beta,
    float* __restrict__ out,
    short* __restrict__ xk,
    short* __restrict__ xv,
    float2* __restrict__ sb,
    float* __restrict__ colsum,
    int* __restrict__ dflag,
    int* __restrict__ scanDone,
    int* __restrict__ qflags)
{
  __shared__ __align__(16) char smem[131072];
  short (*KsD)[64 * 256] = (short (*)[64 * 256])smem;             // 2 x 32 KB
  short (*VtD)[2 * 8192] = (short (*)[2 * 8192])(smem + 65536);   // 2 x 32 KB
  float* Xt = (float*)smem;   // 64 x XSTR fp32 (phase A only, aliases bufs)

  const int i0 = blockIdx.x;
  const int x8 = i0 & 7;            // XCD id (round-robin dispatch heuristic)
  const int s  = i0 >> 3;
  const int b  = x8 + 8 * (s & 7);  // batches = x8 (mod 8) cluster on XCD x8
  const int t  = s >> 3;            // 0..3

  const int tid  = threadIdx.x;
  const int w    = tid >> 6;
  const int lane = tid & 63;
  const int quad = lane >> 4;
  const int r    = lane & 15;

  // ---- phase 0: mask dtype scan + grid counter-barrier
  if (tid < 64) {
    unsigned int v = mw[i0 * 64 + tid];          // 256*64 = 16384 words (safe)
    unsigned long long bl = __ballot(v > 1u);
    if (tid == 0 && bl) atomicOr(dflag, 1);
  }
  __syncthreads();
  if (tid == 0) {
    __threadfence();
    atomicAdd(scanDone, 1);
    while (__hip_atomic_load(scanDone, __ATOMIC_ACQUIRE, __HIP_MEMORY_SCOPE_AGENT) < 256)
      __builtin_amdgcn_s_sleep(2);
  }
  __syncthreads();
  const int df = __hip_atomic_load(dflag, __ATOMIC_RELAXED, __HIP_MEMORY_SCOPE_AGENT);

  // ---- phase A: convert this block's 256 rows
  const float* xb = x + (size_t)b * (T_ * C_);
  short* xkb = xk + (size_t)(b * 1024) * 256;
  float cpart = 0.f;
  const int ccol = tid & 255, chalf = tid >> 8;

  for (int sub = 0; sub < 4; ++sub) {
    const int r0 = t * 256 + sub * 64;
    // rows -> Xt fp32 + swizzled bf16 K image (coalesced)
#pragma unroll
    for (int u = 0; u < 4; ++u) {
      int id = u * 512 + tid, row = id >> 5, ck = id & 31;
      const float* src = xb + (size_t)(r0 + row) * 256 + ck * 8;
      float4 a  = *(const float4*)src;
      float4 c4 = *(const float4*)(src + 4);
      *(float4*)&Xt[row * XSTR + ck * 8]     = a;
      *(float4*)&Xt[row * XSTR + ck * 8 + 4] = c4;
      S8 sv; sv.w[0] = pk2(a.x, a.y);  sv.w[1] = pk2(a.z, a.w);
             sv.w[2] = pk2(c4.x, c4.y); sv.w[3] = pk2(c4.z, c4.w);
      *(short8*)(xkb + (size_t)(r0 + row) * 256 + ((ck ^ ((r0 + row) & 31)) << 3)) = sv.v;
    }
    __syncthreads();
    // transpose -> V^T image, fully coalesced global writes
#pragma unroll
    for (int pass = 0; pass < 4; ++pass) {
      int aG = pass * 512 + tid;            // 2048 chunks = 2 tiles x 1024
      int tileL = aG >> 10, a = aG & 1023;
      int q = a >> 8, c = ((a & 255) - (q << 2)) & 255;
      int jb = tileL * 32 + q * 8;
      float vs[8];
#pragma unroll
      for (int e = 0; e < 8; ++e) vs[e] = Xt[(jb + e) * XSTR + c];
      S8 o;
      o.w[0] = pk2(vs[0], vs[1]); o.w[1] = pk2(vs[2], vs[3]);
      o.w[2] = pk2(vs[4], vs[5]); o.w[3] = pk2(vs[6], vs[7]);
      *(short8*)(xv + (size_t)(b * 32 + t * 8 + sub * 2 + tileL) * 8192 + (aG & 1023) * 8) = o.v;
    }
    // colsum partial (column ccol, half chalf)
#pragma unroll
    for (int e = 0; e < 32; ++e) cpart += Xt[(chalf * 32 + e) * XSTR + ccol];
    __syncthreads();
  }
  atomicAdd(&colsum[b * C_ + ccol], cpart);
  if (tid < 256) {   // sb for this block's rows
    int idx = b * 1024 + t * 256 + tid;
    unsigned int wv = mw[df ? (idx >> 2) : idx];
    unsigned int v = df ? ((wv >> ((idx & 3) * 8)) & 0xffu) : wv;
    sb[idx] = v ? make_float2(0.0625f, 0.f) : make_float2(0.f, NEGF);
  }
  __syncthreads();
  if (tid == 0) {
    __threadfence();
    __hip_atomic_store(&qflags[b * 4 + t], 1, __ATOMIC_RELEASE, __HIP_MEMORY_SCOPE_AGENT);
  }

  // ---- quarter gating
  unsigned seen = 1u << t;
#define GATE(q)                                                                     \
  if (!(seen & (1u << (q)))) {                                                      \
    while (__hip_atomic_load(&qflags[b * 4 + (q)], __ATOMIC_ACQUIRE,                \
                             __HIP_MEMORY_SCOPE_AGENT) == 0)                        \
      __builtin_amdgcn_s_sleep(2);                                                  \
    seen |= 1u << (q);                                                              \
  }

  const int h0len = 2 * (t + 1);

  // ---- state for first q-tile (qt = t)
  int qt   = t;
  int n0   = qt * 128 + w * 16;
  int qrow = n0 + r;
  short8 qf[8];
  GATE(t >> 1);
  {
    const short* qp = xk + (size_t)(b * 1024 + qrow) * 256;
#pragma unroll
    for (int ks = 0; ks < 8; ++ks)
      qf[ks] = *(const short8*)(qp + (((ks * 4 + quad) ^ (qrow & 31)) << 3));
  }
  f32x4 Oa[16];
#pragma unroll
  for (int ct = 0; ct < 16; ++ct) Oa[ct] = (f32x4){0.f, 0.f, 0.f, 0.f};
  float m = NEGF, l = 0.f;

  // prefetch tile 0 into buf 0
  GATE(0);
  {
    const short* gk = xk + (size_t)(b * 1024) * 256;
    const short* gv = xv + (size_t)(b * 32) * 8192;
#pragma unroll
    for (int u = 0; u < 4; ++u) {
      int seg = w * 4 + u;
      async16(gk + seg * 512 + lane * 8, &KsD[0][seg * 512]);
      async16(gv + seg * 512 + lane * 8, &VtD[0][seg * 512]);
    }
  }
  __syncthreads();

  for (int idx = 0; idx < 18; ++idx) {
    const int ibuf = idx & 1;
    if (idx < 17) {   // async prefetch tile(idx+1)
      const int nt2 = (idx + 1 < h0len) ? (idx + 1) : (17 - (idx + 1));
      GATE(nt2 >> 2);
      const short* gk = xk + (size_t)(b * 1024 + nt2 * 64) * 256;
      const short* gv = xv + (size_t)(b * 32 + nt2 * 2) * 8192;
#pragma unroll
      for (int u = 0; u < 4; ++u) {
        int seg = w * 4 + u;
        async16(gk + seg * 512 + lane * 8, &KsD[1 - ibuf][seg * 512]);
        async16(gv + seg * 512 + lane * 8, &VtD[1 - ibuf][seg * 512]);
      }
    }

    const int kt  = (idx < h0len) ? idx : (17 - idx);
    const int ktb = kt * 64;
    if (ktb <= n0 + 15) {   // wave-uniform causal tile skip
      float sc[16];
#pragma unroll
      for (int mt = 0; mt < 4; ++mt) {
        f32x4 acc = (f32x4){0.f, 0.f, 0.f, 0.f};
        const int row = mt * 16 + r;
#pragma unroll
        for (int ks = 0; ks < 8; ++ks) {
          short8 af = *(short8*)&KsD[ibuf][row * 256 + (((ks * 4 + quad) ^ (row & 31)) << 3)];
          acc = __builtin_amdgcn_mfma_f32_16x16x32_bf16(af, qf[ks], acc, 0, 0, 0);
        }
        const int j0 = ktb + mt * 16 + quad * 4;
        float4 sA = *(const float4*)(sb + (size_t)b * 1024 + j0);
        float4 sB = *(const float4*)(sb + (size_t)b * 1024 + j0 + 2);
        sc[mt * 4 + 0] = acc[0] * sA.x + sA.y;
        sc[mt * 4 + 1] = acc[1] * sA.z + sA.w;
        sc[mt * 4 + 2] = acc[2] * sB.x + sB.y;
        sc[mt * 4 + 3] = acc[3] * sB.z + sB.w;
      }
      if (ktb + 63 > n0) {
#pragma unroll
        for (int k2 = 0; k2 < 16; ++k2) {
          int j = ktb + (k2 >> 2) * 16 + quad * 4 + (k2 & 3);
          if (j > qrow) sc[k2] = NEGF;
        }
      }

      float mx = sc[0];
#pragma unroll
      for (int k2 = 1; k2 < 16; ++k2) mx = fmaxf(mx, sc[k2]);
      mx = fmaxf(mx, __shfl_xor(mx, 16, 64));
      mx = fmaxf(mx, __shfl_xor(mx, 32, 64));
      float mnew  = fmaxf(m, mx);
      float alpha = __expf(m - mnew);   // NEGF-NEGF=0 -> 1; NEGF-real -> 0
      float p[16], ps = 0.f;
#pragma unroll
      for (int k2 = 0; k2 < 16; ++k2) { p[k2] = __expf(sc[k2] - mnew); ps += p[k2]; }
      ps += __shfl_xor(ps, 16, 64);
      ps += __shfl_xor(ps, 32, 64);
      l = l * alpha + ps;
      m = mnew;

      if (__ballot(alpha < 1.0f)) {
        float ar[4];
#pragma unroll
        for (int reg = 0; reg < 4; ++reg) ar[reg] = __shfl(alpha, quad * 4 + reg, 64);
#pragma unroll
        for (int ct = 0; ct < 16; ++ct) {
          Oa[ct][0] *= ar[0]; Oa[ct][1] *= ar[1];
          Oa[ct][2] *= ar[2]; Oa[ct][3] *= ar[3];
        }
      }

      S8 pf[2];
#pragma unroll
      for (int hh = 0; hh < 2; ++hh) {
        unsigned q0 = pk2(p[hh * 8 + 0], p[hh * 8 + 1]);
        unsigned q1 = pk2(p[hh * 8 + 2], p[hh * 8 + 3]);
        unsigned q2 = pk2(p[hh * 8 + 4], p[hh * 8 + 5]);
        unsigned q3 = pk2(p[hh * 8 + 6], p[hh * 8 + 7]);
        int s0l = ((quad & 1) << 5) + r, s1l = s0l + 16;
        unsigned u0 = __shfl((int)q0, s0l, 64), u1 = __shfl((int)q1, s0l, 64);
        unsigned u2 = __shfl((int)q2, s0l, 64), u3 = __shfl((int)q3, s0l, 64);
        unsigned v0 = __shfl((int)q0, s1l, 64), v1 = __shfl((int)q1, s1l, 64);
        unsigned v2 = __shfl((int)q2, s1l, 64), v3 = __shfl((int)q3, s1l, 64);
        bool hi = quad >= 2;
        pf[hh].w[0] = hi ? u2 : u0; pf[hh].w[1] = hi ? u3 : u1;
        pf[hh].w[2] = hi ? v2 : v0; pf[hh].w[3] = hi ? v3 : v1;
      }

#pragma unroll
      for (int ct = 0; ct < 16; ++ct) {
        int c = ct * 16 + r;
        int a0 = (quad << 8) + ((c + (quad << 2)) & 255);   // producer-coalesced layout
        short8 b0 = *(short8*)&VtD[ibuf][a0 << 3];
        short8 b1 = *(short8*)&VtD[ibuf][8192 + (a0 << 3)];
        Oa[ct] = __builtin_amdgcn_mfma_f32_16x16x32_bf16(pf[0].v, b0, Oa[ct], 0, 0, 0);
        Oa[ct] = __builtin_amdgcn_mfma_f32_16x16x32_bf16(pf[1].v, b1, Oa[ct], 0, 0, 0);
      }
    }

    // ---- boundary: finalize qt=t, reset for qt=7-t (no LDS touched)
    if (idx == h0len - 1) {
      GATE(0); GATE(1); GATE(2); GATE(3);   // colsum complete
      finalize_tile(Oa, m, l, b, quad, r, colsum, gamma, beta, out);
      qt = 7 - t;
      n0 = qt * 128 + w * 16;
      qrow = n0 + r;
      GATE(qt >> 1);
      const short* qp = xk + (size_t)(b * 1024 + qrow) * 256;
#pragma unroll
      for (int ks = 0; ks < 8; ++ks)
        qf[ks] = *(const short8*)(qp + (((ks * 4 + quad) ^ (qrow & 31)) << 3));
#pragma unroll
      for (int ct = 0; ct < 16; ++ct) Oa[ct] = (f32x4){0.f, 0.f, 0.f, 0.f};
      m = NEGF; l = 0.f;
    }

    __syncthreads();   // drains prefetched tile(idx+1) (issued a full tile ago)
  }

  finalize_tile(Oa, m, l, b, quad, r, colsum, gamma, beta, out);
#undef GATE
}

// ---------------- launch ----------------

extern "C" void kernel_launch(void* const* d_in, const int* in_sizes, int n_in,
                              void* d_out, int out_size, void* d_ws, size_t ws_size,
                              hipStream_t stream) {
  const float* x     = (const float*)d_in[0];
  const void*  km    = d_in[1];
  const float* gamma = (const float*)d_in[2];
  const float* beta  = (const float*)d_in[3];
  float* out = (float*)d_out;

  // ws layout: colsum @0 (64 KB) | dflag @65536 | scanDone @65540 |
  //            qflags @65544 (1 KB) | sb @131200 (512 KB) | xk @655616 (32 MB) | xv (32 MB)
  const size_t off_sb = 131200;
  const size_t off_xk = 655616;
  const size_t off_xv = off_xk + 33554432;

  float*  colsum   = (float*)d_ws;
  int*    dflag    = (int*)((char*)d_ws + 65536);
  int*    scanDone = (int*)((char*)d_ws + 65540);
  int*    qflags   = (int*)((char*)d_ws + 65544);
  float2* sb       = (float2*)((char*)d_ws + off_sb);
  short*  xk       = (short*)((char*)d_ws + off_xk);
  short*  xv       = (short*)((char*)d_ws + off_xv);

  hipMemsetAsync(d_ws, 0, 66568, stream);    // colsum + dflag + scanDone + qflags
  hipMemsetAsync(d_out, 0, 65536, stream);   // out accumulated atomically
  flash6<<<256, 512, 0, stream>>>(x, (const unsigned int*)km, gamma, beta, out,
                                  xk, xv, sb, colsum, dflag, scanDone, qflags);
}